// Round 10
// baseline (664.640 us; speedup 1.0000x reference)
//
#include <hip/hip_runtime.h>

#define T_TOK 1024
#define H_DIM 1024
#define I_DIM 768
#define E_NUM 8

#define NBLK 768             // cooperative grid: 3 blocks/CU x 256 CU
#define G13 1572864          // 8*1536*1024/8
#define G2   786432          // 8*1024*768/8
#define GX   131072

#define SLOT 24576           // ring slot: B 16KB + A 8KB
#define A_OFF 16384

// ctrl flag indices (stride-16 ints)
#define C_RTR   0
#define C_XCNT  16
#define C_P2    32
#define C_PAIR(P)  (48 + (P) * 16)      // 96 pair flags (target 8)
#define C_STRIP(s) (1584 + (s) * 16)    // 128 strip flags (target 12)
#define C_TOTAL 3632
#define CTRL_BYTES (C_TOTAL * 4)

typedef __bf16 bf16x8 __attribute__((ext_vector_type(8)));
typedef float  f32x4  __attribute__((ext_vector_type(4)));

struct SB {
    union { uint4 r4[2 * SLOT / 16]; float gu[64 * 132]; } u;   // 49152 B
    int tokS[64];
    int cnt[E_NUM];
};

struct StgEnt { const char* p; int l; };

__device__ inline bf16x8 cvt8(float4 a, float4 b, float s) {
    bf16x8 o;
    o[0] = (__bf16)(a.x * s); o[1] = (__bf16)(a.y * s);
    o[2] = (__bf16)(a.z * s); o[3] = (__bf16)(a.w * s);
    o[4] = (__bf16)(b.x * s); o[5] = (__bf16)(b.y * s);
    o[6] = (__bf16)(b.z * s); o[7] = (__bf16)(b.w * s);
    return o;
}

__device__ inline void async16(const void* g, void* l) {
    __builtin_amdgcn_global_load_lds(
        (const __attribute__((address_space(1))) unsigned int*)g,
        (__attribute__((address_space(3))) unsigned int*)l, 16, 0, 0);
}

#define VM_WAIT6  asm volatile("s_waitcnt vmcnt(6)"  ::: "memory")
#define VM_WAIT0  asm volatile("s_waitcnt vmcnt(0)"  ::: "memory")
#define MFMA(A, B, C) __builtin_amdgcn_mfma_f32_16x16x32_bf16(A, B, C, 0, 0, 0)

__device__ __forceinline__ void wait_ge(int* p, int v) {
    while (atomicAdd(p, 0) < v) __builtin_amdgcn_s_sleep(2);
}

// ---- w13 dequant: one (P, s) chunk = 16 rows, 8 iters x 256 thr ----------
__device__ __forceinline__ void dq13_chunk(int P, int s, int tid,
    const float* __restrict__ w13, const float* __restrict__ w13s,
    __bf16* __restrict__ w13d)
{
    const int e = P / 12, nb = P % 12;
    const int n0rel = (s < 4) ? (nb * 64 + s * 16)
                              : (I_DIM + nb * 64 + (s - 4) * 16);
    const size_t gb = (size_t)(e * 1536 + n0rel) * 128;
#pragma unroll
    for (int k = 0; k < 8; k++) {
        size_t g = gb + k * 256 + tid;
        int row = (int)(g >> 7), k8 = (int)(g & 127);
        float sc = w13s[(row << 3) | (k8 >> 4)];
        const float4* src = (const float4*)w13 + g * 2;
        *(bf16x8*)(w13d + g * 8) = cvt8(src[0], src[1], sc);
    }
}

__device__ __forceinline__ void w2dq_elems(int start, int stride,
    const float* __restrict__ w2, const float* __restrict__ w2s,
    __bf16* __restrict__ w2d)
{
    for (int g2 = start; g2 < G2; g2 += stride) {
        unsigned row = (unsigned)g2 / 96u;
        int k8 = g2 - (int)row * 96;
        float sc = w2s[row * 6 + (k8 >> 4)];
        const float4* src = (const float4*)w2 + (size_t)g2 * 2;
        *(bf16x8*)(w2d + (size_t)g2 * 8) = cvt8(src[0], src[1], sc);
    }
}

__device__ __forceinline__ void zero_out(int start, int stride, float4* out4) {
    float4 z = make_float4(0.f, 0.f, 0.f, 0.f);
    for (int i = start; i < 262144; i += stride) out4[i] = z;
}

__device__ __forceinline__ void router_dev(int tid, int* cnt,
    const float* __restrict__ logits,
    int* __restrict__ counts, int* __restrict__ base,
    int* __restrict__ tok_list, float* __restrict__ wt_list)
{
    if (tid < E_NUM) cnt[tid] = 0;
    __syncthreads();
#pragma unroll
    for (int tt = 0; tt < 4; tt++) {
        int t = tid + tt * 256;
        float l[E_NUM];
#pragma unroll
        for (int e = 0; e < E_NUM; e++) l[e] = logits[t * E_NUM + e];
        int e0 = 0; float m0 = l[0];
#pragma unroll
        for (int e = 1; e < E_NUM; e++) if (l[e] > m0) { m0 = l[e]; e0 = e; }
        int e1 = -1; float m1 = -3e38f;
#pragma unroll
        for (int e = 0; e < E_NUM; e++) if (e != e0 && l[e] > m1) { m1 = l[e]; e1 = e; }
        float w0 = 1.0f / (1.0f + expf(m1 - m0));
        float w1 = 1.0f - w0;
        int p0 = atomicAdd(&cnt[e0], 1);
        tok_list[e0 * T_TOK + p0] = t;
        wt_list[e0 * T_TOK + p0] = w0;
        int p1 = atomicAdd(&cnt[e1], 1);
        tok_list[e1 * T_TOK + p1] = t;
        wt_list[e1 * T_TOK + p1] = w1;
    }
    __syncthreads();
    if (tid == 0) {
        int s = 0;
        for (int e = 0; e < E_NUM; e++) { base[e] = s; counts[e] = cnt[e]; s += cnt[e]; }
    }
}

// ---- GEMM1 tile body (R8-proven): M64 x N128, K=16*64, ring-2, vmcnt(6) --
__device__ __forceinline__ void gemm1_tile(
    int e, int nb, int m0, int count, int abase, int tid, SB* sh,
    const __bf16* __restrict__ xbf, const __bf16* __restrict__ w13d,
    const int* __restrict__ tok_list, __bf16* __restrict__ act)
{
    char* ring = (char*)sh->u.r4;
    const int n0 = nb * 64;
    if (tid < 64) {
        int r = m0 + tid;
        sh->tokS[tid] = (r < count) ? tok_list[e * T_TOK + r] : tok_list[e * T_TOK];
    }
    __syncthreads();

    const int wv = tid >> 6, ln = tid & 63;
    StgEnt se[6];
#pragma unroll
    for (int j = 0; j < 6; j++) {
        int off = wv * 6144 + j * 1024 + ln * 16;
        se[j].l = wv * 6144 + j * 1024;
        if (off < A_OFF) {
            int r = off >> 7, sl = (off >> 4) & 7, g = sl ^ (r & 7);
            int nB = (r < 64) ? (n0 + r) : (I_DIM + n0 + r - 64);
            se[j].p = (const char*)w13d + ((size_t)e * 2 * I_DIM + nB) * 2048 + g * 16;
        } else {
            int ao = off - A_OFF, r = ao >> 7, sl = (ao >> 4) & 7, g = sl ^ (r & 7);
            se[j].p = (const char*)xbf + (size_t)sh->tokS[r] * 2048 + g * 16;
        }
    }

#define ISSUE_G1(kc, sb) do { \
        async16(se[0].p + (kc) * 128, (sb) + se[0].l); \
        async16(se[1].p + (kc) * 128, (sb) + se[1].l); \
        async16(se[2].p + (kc) * 128, (sb) + se[2].l); \
        async16(se[3].p + (kc) * 128, (sb) + se[3].l); \
        async16(se[4].p + (kc) * 128, (sb) + se[4].l); \
        async16(se[5].p + (kc) * 128, (sb) + se[5].l); } while (0)

    const int wid = wv, lane = ln, lrow = lane & 15, quad = lane >> 4;
    int aoff[2][4], boff[2][2];
#pragma unroll
    for (int kk = 0; kk < 2; kk++) {
        int gph = ((kk * 4 + quad) ^ (lrow & 7)) << 4;
#pragma unroll
        for (int i = 0; i < 4; i++) aoff[kk][i] = (i * 16 + lrow) * 128 + gph;
#pragma unroll
        for (int j = 0; j < 2; j++) boff[kk][j] = (wid * 32 + j * 16 + lrow) * 128 + gph;
    }

    f32x4 acc[4][2];
#pragma unroll
    for (int i = 0; i < 4; i++)
#pragma unroll
        for (int j = 0; j < 2; j++) { f32x4 z = {0.f, 0.f, 0.f, 0.f}; acc[i][j] = z; }

    auto compute = [&](const char* sb) {
        const char* Bb = sb;
        const char* Ab = sb + A_OFF;
#pragma unroll
        for (int kk = 0; kk < 2; kk++) {
            bf16x8 b0 = *(const bf16x8*)(Bb + boff[kk][0]);
            bf16x8 b1 = *(const bf16x8*)(Bb + boff[kk][1]);
#pragma unroll
            for (int i = 0; i < 4; i++) {
                bf16x8 a = *(const bf16x8*)(Ab + aoff[kk][i]);
                acc[i][0] = MFMA(a, b0, acc[i][0]);
                acc[i][1] = MFMA(a, b1, acc[i][1]);
            }
        }
    };

    VM_WAIT0;   // exact vmcnt baseline
    ISSUE_G1(0, ring);
#pragma unroll
    for (int k = 0; k < 16; k++) {
        if (k + 1 < 16) ISSUE_G1(k + 1, ring + ((k + 1) & 1) * SLOT);
        if (k < 15) { VM_WAIT6; } else { VM_WAIT0; }
        __builtin_amdgcn_s_barrier();
        compute(ring + (k & 1) * SLOT);
        __builtin_amdgcn_s_barrier();
    }
#undef ISSUE_G1

#pragma unroll
    for (int i = 0; i < 4; i++)
#pragma unroll
        for (int j = 0; j < 2; j++)
#pragma unroll
            for (int r = 0; r < 4; r++) {
                int mr = i * 16 + quad * 4 + r;
                int c = wid * 32 + j * 16 + lrow;
                sh->u.gu[mr * 132 + c] = acc[i][j][r];
            }
    __syncthreads();

#pragma unroll
    for (int ii = 0; ii < 16; ii++) {
        int o = ii * 256 + tid;
        int mr = o >> 6, c = o & 63;
        if (m0 + mr < count) {
            float g  = sh->u.gu[mr * 132 + c];
            float up = sh->u.gu[mr * 132 + 64 + c];
            float a  = g / (1.0f + expf(-g)) * up;
            act[(size_t)(abase + m0 + mr) * I_DIM + n0 + c] = (__bf16)a;
        }
    }
}

// ---- GEMM2 tile body (R8-proven): M64 x N128, K=12*64 --------------------
__device__ __forceinline__ void gemm2_tile(
    int e, int nb, int m0, int count, int abase, int tid, SB* sh,
    const __bf16* __restrict__ act, const __bf16* __restrict__ w2d,
    const int* __restrict__ tok_list, const float* __restrict__ wt_list,
    float* __restrict__ out)
{
    char* ring = (char*)sh->u.r4;
    const int n0 = nb * 128;
    __syncthreads();    // LDS reuse guard

    const int wv = tid >> 6, ln = tid & 63;
    StgEnt se[6];
#pragma unroll
    for (int j = 0; j < 6; j++) {
        int off = wv * 6144 + j * 1024 + ln * 16;
        se[j].l = wv * 6144 + j * 1024;
        if (off < A_OFF) {
            int r = off >> 7, sl = (off >> 4) & 7, g = sl ^ (r & 7);
            se[j].p = (const char*)w2d + ((size_t)e * H_DIM + n0 + r) * 1536 + g * 16;
        } else {
            int ao = off - A_OFF, r = ao >> 7, sl = (ao >> 4) & 7, g = sl ^ (r & 7);
            int gr = abase + m0 + r; if (gr > 2 * T_TOK - 1) gr = 2 * T_TOK - 1;
            se[j].p = (const char*)act + (size_t)gr * 1536 + g * 16;
        }
    }

#define ISSUE_G2(kc, sb) do { \
        async16(se[0].p + (kc) * 128, (sb) + se[0].l); \
        async16(se[1].p + (kc) * 128, (sb) + se[1].l); \
        async16(se[2].p + (kc) * 128, (sb) + se[2].l); \
        async16(se[3].p + (kc) * 128, (sb) + se[3].l); \
        async16(se[4].p + (kc) * 128, (sb) + se[4].l); \
        async16(se[5].p + (kc) * 128, (sb) + se[5].l); } while (0)

    const int wid = wv, lane = ln, lrow = lane & 15, quad = lane >> 4;
    int aoff[2][4], boff[2][2];
#pragma unroll
    for (int kk = 0; kk < 2; kk++) {
        int gph = ((kk * 4 + quad) ^ (lrow & 7)) << 4;
#pragma unroll
        for (int i = 0; i < 4; i++) aoff[kk][i] = (i * 16 + lrow) * 128 + gph;
#pragma unroll
        for (int j = 0; j < 2; j++) boff[kk][j] = (wid * 32 + j * 16 + lrow) * 128 + gph;
    }

    f32x4 acc[4][2];
#pragma unroll
    for (int i = 0; i < 4; i++)
#pragma unroll
        for (int j = 0; j < 2; j++) { f32x4 z = {0.f, 0.f, 0.f, 0.f}; acc[i][j] = z; }

    auto compute = [&](const char* sb) {
        const char* Bb = sb;
        const char* Ab = sb + A_OFF;
#pragma unroll
        for (int kk = 0; kk < 2; kk++) {
            bf16x8 b0 = *(const bf16x8*)(Bb + boff[kk][0]);
            bf16x8 b1 = *(const bf16x8*)(Bb + boff[kk][1]);
#pragma unroll
            for (int i = 0; i < 4; i++) {
                bf16x8 a = *(const bf16x8*)(Ab + aoff[kk][i]);
                acc[i][0] = MFMA(a, b0, acc[i][0]);
                acc[i][1] = MFMA(a, b1, acc[i][1]);
            }
        }
    };

    VM_WAIT0;
    ISSUE_G2(0, ring);
#pragma unroll
    for (int k = 0; k < 12; k++) {
        if (k + 1 < 12) ISSUE_G2(k + 1, ring + ((k + 1) & 1) * SLOT);
        if (k < 11) { VM_WAIT6; } else { VM_WAIT0; }
        __builtin_amdgcn_s_barrier();
        compute(ring + (k & 1) * SLOT);
        __builtin_amdgcn_s_barrier();
    }
#undef ISSUE_G2

#pragma unroll
    for (int i = 0; i < 4; i++)
#pragma unroll
        for (int r = 0; r < 4; r++) {
            int mr = i * 16 + quad * 4 + r;
            if (m0 + mr < count) {
                int   tk = tok_list[e * T_TOK + m0 + mr];
                float w  = wt_list[e * T_TOK + m0 + mr];
#pragma unroll
                for (int j = 0; j < 2; j++) {
                    int h = n0 + wid * 32 + j * 16 + lrow;
                    atomicAdd(&out[(size_t)tk * H_DIM + h], w * acc[i][j][r]);
                }
            }
        }
}

// ===================== cooperative kernel: static assignment ==============
// 768 co-resident blocks (3/CU). Per block:
//   A: x share + one w13 dq chunk (no gates -> full-BW streaming)
//   C: (blocks >=384 only) w2 dequant + out zero  -> C_P2
//   B: gemm1 tile v=b (+768), gated RTR/XCNT/PAIR -> STRIP
//   D: gemm2 tile v=767-b (+ 1535-b), gated C_P2 + STRIP
// Co-residency (cooperative launch) makes all spins deadlock-free.
__global__ __launch_bounds__(256, 3) void moe_coop(
    const float* __restrict__ x, const float* __restrict__ logits,
    const float* __restrict__ w13, const float* __restrict__ w13s,
    const float* __restrict__ w2, const float* __restrict__ w2s,
    float* __restrict__ out,
    int* counts, int* base, int* tok_list, float* wt_list,
    __bf16* act, __bf16* xbf, __bf16* w13d, __bf16* w2d,
    int* ctrl)
{
    __shared__ SB sh;
    const int b = blockIdx.x, tid = threadIdx.x;

    // ---- phase A ----
    {
        int i = b * 256 + tid;
        if (i < GX) {
            const float4* src = (const float4*)x + (size_t)i * 2;
            *(bf16x8*)(xbf + (size_t)i * 8) = cvt8(src[0], src[1], 1.0f);
        }
    }
    if (b < 512) {
        __threadfence(); __syncthreads();
        if (tid == 0) atomicAdd(&ctrl[C_XCNT], 1);
    }
    if (b == 767) {
        router_dev(tid, sh.cnt, logits, counts, base, tok_list, wt_list);
        __threadfence(); __syncthreads();
        if (tid == 0) atomicAdd(&ctrl[C_RTR], 1);
    }
    dq13_chunk(b >> 3, b & 7, tid, w13, w13s, w13d);
    __threadfence(); __syncthreads();
    if (tid == 0) atomicAdd(&ctrl[C_PAIR(b >> 3)], 1);

    // ---- phase C (gemm1-idle blocks): w2 dequant + out zero ----
    if (b >= 384) {
        zero_out((b - 384) * 256 + tid, 98304, (float4*)out);
        w2dq_elems((b - 384) * 256 + tid, 98304, w2, w2s, w2d);
        __threadfence(); __syncthreads();
        if (tid == 0) atomicAdd(&ctrl[C_P2], 1);
    }

    // ---- phase B: gemm1 ----
    {
        bool gated = false;
        for (int vi = 0; vi < 2; vi++) {
            const int v = b + vi * 768;
            const int xcd = v & 7, t = v >> 3;
            const int p = t % 12, m = t / 12;
            const int P = xcd + 8 * p;
            const int nb = P % 12, e = P / 12;
            if (!gated) {
                if (tid == 0) { wait_ge(&ctrl[C_RTR], 1); wait_ge(&ctrl[C_XCNT], 512); }
                __syncthreads(); __threadfence();
                gated = true;
            }
            const int count = counts[e];
            const int m0 = m * 64;
            if (m0 >= count) continue;
            if (tid == 0) wait_ge(&ctrl[C_PAIR(P)], 8);
            __syncthreads(); __threadfence();
            gemm1_tile(e, nb, m0, count, base[e], tid, &sh, xbf, w13d, tok_list, act);
            __threadfence(); __syncthreads();
            if (tid == 0) atomicAdd(&ctrl[C_STRIP(e * 16 + m)], 1);
        }
    }

    // ---- phase D: gemm2 (reversed mapping: live tiles on gemm1-idle blocks)
    {
        bool gated2 = false;
        for (int vi = 0; vi < 2; vi++) {
            if (vi == 1 && b < 512) continue;
            const int v = (vi == 0) ? (767 - b) : (1535 - b);   // covers [0,1024)
            const int xcd = v & 7, t = v >> 3;
            const int p = t & 7, m = t >> 3;
            const int P2 = xcd + 8 * p;
            const int nb = P2 & 7, e = P2 >> 3;
            const int count = counts[e];
            const int m0 = m * 64;
            if (m0 >= count) continue;
            if (!gated2) {
                if (tid == 0) wait_ge(&ctrl[C_P2], 384);
                __syncthreads(); __threadfence();
                gated2 = true;
            }
            if (tid == 0) wait_ge(&ctrl[C_STRIP(e * 16 + m)], 12);
            __syncthreads(); __threadfence();
            gemm2_tile(e, nb, m0, count, base[e], tid, &sh, act, w2d, tok_list, wt_list, out);
        }
    }
}

// ===================== fallback (non-cooperative, R8-equivalent) ==========
__global__ __launch_bounds__(256) void fb_prep(
    const float* __restrict__ x, const float* __restrict__ logits,
    const float* __restrict__ w13, const float* __restrict__ w13s,
    __bf16* __restrict__ w13d, __bf16* __restrict__ xbf,
    int* counts, int* base, int* tok_list, float* wt_list)
{
    const int b = blockIdx.x, tid = threadIdx.x;
    if (b < 768) {
        int i = b * 256 + tid;
        if (i < GX) {
            const float4* src = (const float4*)x + (size_t)i * 2;
            *(bf16x8*)(xbf + (size_t)i * 8) = cvt8(src[0], src[1], 1.0f);
        }
        dq13_chunk(b >> 3, b & 7, tid, w13, w13s, w13d);
        return;
    }
    __shared__ int cnt[E_NUM];
    router_dev(tid, cnt, logits, counts, base, tok_list, wt_list);
}

__global__ __launch_bounds__(256, 3) void fb_gemm1(
    const __bf16* __restrict__ xbf, const __bf16* __restrict__ w13d,
    const int* __restrict__ counts, const int* __restrict__ base,
    const int* __restrict__ tok_list, __bf16* __restrict__ act,
    const float* __restrict__ w2, const float* __restrict__ w2s,
    __bf16* __restrict__ w2d, float* __restrict__ out)
{
    const int bx = blockIdx.x, tid = threadIdx.x;
    if (bx >= 1536) {
        const int q = bx - 1536;                        // 1024 BW blocks
        zero_out(q * 256 + tid, 262144, (float4*)out);
        w2dq_elems(q * 256 + tid, 262144, w2, w2s, w2d);
        return;
    }
    const int xcd = bx & 7, t = bx >> 3;
    const int p = t % 12, m = t / 12;
    const int P = xcd + 8 * p;
    const int nb = P % 12, e = P / 12;
    const int count = counts[e];
    const int m0 = m * 64;
    if (m0 >= count) return;
    __shared__ SB sh;
    gemm1_tile(e, nb, m0, count, base[e], tid, &sh, xbf, w13d, tok_list, act);
}

__global__ __launch_bounds__(256, 3) void fb_gemm2(
    const __bf16* __restrict__ act, const __bf16* __restrict__ w2d,
    const int* __restrict__ counts, const int* __restrict__ base,
    const int* __restrict__ tok_list, const float* __restrict__ wt_list,
    float* __restrict__ out)
{
    const int v = blockIdx.x, tid = threadIdx.x;
    const int xcd = v & 7, t = v >> 3;
    const int p = t & 7, m = t >> 3;
    const int P2 = xcd + 8 * p;
    const int nb = P2 & 7, e = P2 >> 3;
    const int count = counts[e];
    const int m0 = m * 64;
    if (m0 >= count) return;
    __shared__ SB sh;
    gemm2_tile(e, nb, m0, count, base[e], tid, &sh, act, w2d, tok_list, wt_list, out);
}

extern "C" void kernel_launch(void* const* d_in, const int* in_sizes, int n_in,
                              void* d_out, int out_size, void* d_ws, size_t ws_size,
                              hipStream_t stream) {
    (void)in_sizes; (void)n_in; (void)out_size; (void)ws_size;
    const float* x      = (const float*)d_in[0];
    const float* logits = (const float*)d_in[1];
    const float* w13    = (const float*)d_in[2];
    const float* w13s   = (const float*)d_in[3];
    const float* w2     = (const float*)d_in[4];
    const float* w2s    = (const float*)d_in[5];
    float* out = (float*)d_out;

    char* ws = (char*)d_ws;
    int*    counts   = (int*)ws;                              // @0
    int*    base     = (int*)(ws + 128);                      // @128
    int*    tok_list = (int*)(ws + 256);                      // 32 KB
    float*  wt_list  = (float*)(ws + 256 + 32768);            // 32 KB
    __bf16* act      = (__bf16*)(ws + 65792);                 // 3 MB
    __bf16* xbf      = (__bf16*)(ws + 65792 + 3145728);       // 2 MB
    __bf16* w13d     = (__bf16*)(ws + 65792 + 3145728 + 2097152);            // 25.2 MB
    __bf16* w2d      = (__bf16*)(ws + 65792 + 3145728 + 2097152 + 25165824); // 12.6 MB
    int*    ctrl     = (int*)(ws + 43057408);                 // 14.5 KB flags

    hipMemsetAsync(ctrl, 0, CTRL_BYTES, stream);

    void* kargs[] = { (void*)&x, (void*)&logits, (void*)&w13, (void*)&w13s,
                      (void*)&w2, (void*)&w2s, (void*)&out,
                      (void*)&counts, (void*)&base, (void*)&tok_list, (void*)&wt_list,
                      (void*)&act, (void*)&xbf, (void*)&w13d, (void*)&w2d,
                      (void*)&ctrl };
    hipError_t err = hipLaunchCooperativeKernel(
        (const void*)moe_coop, dim3(NBLK), dim3(256), kargs, 0, stream);
    if (err != hipSuccess) {
        fb_prep<<<dim3(769), 256, 0, stream>>>(
            x, logits, w13, w13s, w13d, xbf, counts, base, tok_list, wt_list);
        fb_gemm1<<<dim3(1536 + 1024), 256, 0, stream>>>(
            xbf, w13d, counts, base, tok_list, act, w2, w2s, w2d, out);
        fb_gemm2<<<dim3(1024), 256, 0, stream>>>(
            act, w2d, counts, base, tok_list, wt_list, out);
    }
}

// Round 11
// 155.129 us; speedup vs baseline: 4.2844x; 4.2844x over previous
//
#include <hip/hip_runtime.h>

#define T_TOK 1024
#define H_DIM 1024
#define I_DIM 768
#define E_NUM 8

// kernelA block ranges (out-zero moved to gemm1 launch)
#define A_W13 6144           // w13 dequant blocks (G13 groups / 256)
#define A_X   512            // x convert
#define G13 1572864          // 8*1536*1024/8
#define G2   786432          // 8*1024*768/8

// gemm1 grid: gemm blocks, then w2-dequant blocks, then out-zero blocks
#define GEMM1_BLOCKS 1536    // 8 xcd * 12 pairs * 16 m-rounds
#define W2DQ_BLOCKS  3072    // G2/256
#define ZERO_BLOCKS  128     // 4 MB out zero

#define SLOT 24576           // ring slot: B 16KB + A 8KB
#define A_OFF 16384

typedef __bf16 bf16x8 __attribute__((ext_vector_type(8)));
typedef float  f32x4  __attribute__((ext_vector_type(4)));

__device__ inline bf16x8 cvt8(float4 a, float4 b, float s) {
    bf16x8 o;
    o[0] = (__bf16)(a.x * s); o[1] = (__bf16)(a.y * s);
    o[2] = (__bf16)(a.z * s); o[3] = (__bf16)(a.w * s);
    o[4] = (__bf16)(b.x * s); o[5] = (__bf16)(b.y * s);
    o[6] = (__bf16)(b.z * s); o[7] = (__bf16)(b.w * s);
    return o;
}

// async 16B global -> LDS (linear dest: wave-uniform base + lane*16)
__device__ inline void async16(const void* g, void* l) {
    __builtin_amdgcn_global_load_lds(
        (const __attribute__((address_space(1))) unsigned int*)g,
        (__attribute__((address_space(3))) unsigned int*)l, 16, 0, 0);
}

#define VM_WAIT6  asm volatile("s_waitcnt vmcnt(6)"  ::: "memory")
#define VM_WAIT0  asm volatile("s_waitcnt vmcnt(0)"  ::: "memory")

// ---- kernelA: w13 dequant + x -> bf16 + router ---------------------------
__global__ __launch_bounds__(256) void prep13_kernel(
    const float* __restrict__ w13, const float* __restrict__ w13s,
    const float* __restrict__ x,
    __bf16* __restrict__ w13d,     __bf16* __restrict__ xbf,
    const float* __restrict__ logits,
    int* __restrict__ counts, int* __restrict__ base,
    int* __restrict__ tok_list, float* __restrict__ wt_list)
{
    const int bx = blockIdx.x;
    if (bx < A_W13) {
        int g = bx * 256 + threadIdx.x;          // < G13
        int k8 = g & 127;                        // 128 groups per 1024-k row
        int row = g >> 7;                        // e*1536 + n
        float s = w13s[(row << 3) | (k8 >> 4)];
        const float4* src = (const float4*)w13 + (size_t)g * 2;
        *(bf16x8*)(w13d + (size_t)g * 8) = cvt8(src[0], src[1], s);
        return;
    }
    if (bx < A_W13 + A_X) {
        int g = (bx - A_W13) * 256 + threadIdx.x;   // < 131072
        const float4* src = (const float4*)x + (size_t)g * 2;
        *(bf16x8*)(xbf + (size_t)g * 8) = cvt8(src[0], src[1], 1.0f);
        return;
    }
    // ---- router (single block) ----
    __shared__ int cnt[E_NUM];
    const int t0 = threadIdx.x;
    if (t0 < E_NUM) cnt[t0] = 0;
    __syncthreads();
#pragma unroll
    for (int tt = 0; tt < 4; tt++) {
        int t = t0 + tt * 256;
        float l[E_NUM];
#pragma unroll
        for (int e = 0; e < E_NUM; e++) l[e] = logits[t * E_NUM + e];
        int e0 = 0; float m0 = l[0];
#pragma unroll
        for (int e = 1; e < E_NUM; e++) if (l[e] > m0) { m0 = l[e]; e0 = e; }
        int e1 = -1; float m1 = -3e38f;
#pragma unroll
        for (int e = 0; e < E_NUM; e++) if (e != e0 && l[e] > m1) { m1 = l[e]; e1 = e; }
        float w0 = 1.0f / (1.0f + expf(m1 - m0));
        float w1 = 1.0f - w0;
        int p0 = atomicAdd(&cnt[e0], 1);
        tok_list[e0 * T_TOK + p0] = t;
        wt_list[e0 * T_TOK + p0] = w0;
        int p1 = atomicAdd(&cnt[e1], 1);
        tok_list[e1 * T_TOK + p1] = t;
        wt_list[e1 * T_TOK + p1] = w1;
    }
    __syncthreads();
    if (t0 == 0) {
        int s = 0;
        for (int e = 0; e < E_NUM; e++) { base[e] = s; counts[e] = cnt[e]; s += cnt[e]; }
    }
}

#define MFMA(A, B, C) __builtin_amdgcn_mfma_f32_16x16x32_bf16(A, B, C, 0, 0, 0)

// Per-thread staging entry: global byte ptr (at K-chunk 0) + wave-uniform LDS
// byte offset within slot. Inverse-swizzled SOURCE + linear LDS dest + the
// proven swizzled ds_read offsets (both-sides-or-neither rule).
struct StgEnt { const char* p; int l; };

// ---- kernelB: GEMM1 (M=64 x N=128, BK=64) + w2-dequant + out-zero --------
// gload_lds staging, 2-slot LDS ring (49 KB -> 3 blocks/CU), counted vmcnt
// (never 0 in loop), raw s_barrier.
__global__ __launch_bounds__(256, 3) void gemm1_kernel(
    const __bf16* __restrict__ xbf,
    const __bf16* __restrict__ w13d,
    const int* __restrict__ counts,
    const int* __restrict__ base,
    const int* __restrict__ tok_list,
    __bf16* __restrict__ act,
    const float* __restrict__ w2,
    const float* __restrict__ w2s,
    __bf16* __restrict__ w2d,
    float4* __restrict__ out4)
{
    const int bx = blockIdx.x;
    if (bx >= GEMM1_BLOCKS + W2DQ_BLOCKS) {
        // ---- out zero (needed only by gemm2: next launch, stream-ordered)
        int zi = bx - (GEMM1_BLOCKS + W2DQ_BLOCKS);
        float4 z = make_float4(0.f, 0.f, 0.f, 0.f);
#pragma unroll
        for (int k = 0; k < 8; k++)
            out4[zi * 2048 + k * 256 + threadIdx.x] = z;
        return;
    }
    if (bx >= GEMM1_BLOCKS) {
        // ---- w2 dequant (no dependency on gemm1; fills idle CUs) ----
        int g2 = (bx - GEMM1_BLOCKS) * 256 + threadIdx.x;   // < G2
        unsigned row = (unsigned)g2 / 96u;   // e*1024 + h
        int k8 = g2 - row * 96;
        float s = w2s[row * 6 + (k8 >> 4)];
        const float4* src = (const float4*)w2 + (size_t)g2 * 2;
        *(bf16x8*)(w2d + (size_t)g2 * 8) = cvt8(src[0], src[1], s);
        return;
    }

    const int xcd = bx & 7, t = bx >> 3;
    const int p = t % 12, m = t / 12;      // 12 pairs per XCD, 16 m rounds
    const int P = xcd + 8 * p;             // pair id in [0,96)
    const int nb = P % 12, e = P / 12;
    const int count = counts[e];
    const int m0 = m * 64;
    if (m0 >= count) return;
    const int n0 = nb * 64;
    const int abase = base[e];

    __shared__ union { uint4 r4[2 * SLOT / 16]; float gu[64 * 132]; } u;  // 49152 B
    __shared__ int tokS[64];
    char* ring = (char*)u.r4;

    const int tid = threadIdx.x;
    if (tid < 64) {
        int r = m0 + tid;
        tokS[tid] = (r < count) ? tok_list[e * T_TOK + r] : tok_list[e * T_TOK];
    }
    __syncthreads();   // also drains vmcnt -> clean pipeline baseline

    const int wv = tid >> 6, ln = tid & 63;
    // 6 staging calls per thread: bytes [wv*6144 + j*1024 + ln*16) of slot.
    // B region [0,16384): LDS row r (128B), slot s holds global granule s^(r&7).
    // A region [16384,24576): same per-row swizzle, rows = tokS.
    StgEnt se[6];
#pragma unroll
    for (int j = 0; j < 6; j++) {
        int off = wv * 6144 + j * 1024 + ln * 16;
        se[j].l = wv * 6144 + j * 1024;          // wave-uniform dest
        if (off < A_OFF) {
            int r = off >> 7, sl = (off >> 4) & 7, g = sl ^ (r & 7);
            int nB = (r < 64) ? (n0 + r) : (I_DIM + n0 + r - 64);
            se[j].p = (const char*)w13d + ((size_t)e * 2 * I_DIM + nB) * 2048 + g * 16;
        } else {
            int ao = off - A_OFF, r = ao >> 7, sl = (ao >> 4) & 7, g = sl ^ (r & 7);
            se[j].p = (const char*)xbf + (size_t)tokS[r] * 2048 + g * 16;
        }
    }

#define ISSUE(kc, sb) do { \
        async16(se[0].p + (kc) * 128, (sb) + se[0].l); \
        async16(se[1].p + (kc) * 128, (sb) + se[1].l); \
        async16(se[2].p + (kc) * 128, (sb) + se[2].l); \
        async16(se[3].p + (kc) * 128, (sb) + se[3].l); \
        async16(se[4].p + (kc) * 128, (sb) + se[4].l); \
        async16(se[5].p + (kc) * 128, (sb) + se[5].l); } while (0)

    const int wid = wv, lane = ln, lrow = lane & 15, quad = lane >> 4;
    int aoff[2][4], boff[2][2];
#pragma unroll
    for (int kk = 0; kk < 2; kk++) {
        int gph = ((kk * 4 + quad) ^ (lrow & 7)) << 4;
#pragma unroll
        for (int i = 0; i < 4; i++) aoff[kk][i] = (i * 16 + lrow) * 128 + gph;
#pragma unroll
        for (int j = 0; j < 2; j++) boff[kk][j] = (wid * 32 + j * 16 + lrow) * 128 + gph;
    }

    f32x4 acc[4][2];
#pragma unroll
    for (int i = 0; i < 4; i++)
#pragma unroll
        for (int j = 0; j < 2; j++) { f32x4 z = {0.f, 0.f, 0.f, 0.f}; acc[i][j] = z; }

    auto compute = [&](const char* sb) {
        const char* Bb = sb;
        const char* Ab = sb + A_OFF;
#pragma unroll
        for (int kk = 0; kk < 2; kk++) {
            bf16x8 b0 = *(const bf16x8*)(Bb + boff[kk][0]);
            bf16x8 b1 = *(const bf16x8*)(Bb + boff[kk][1]);
#pragma unroll
            for (int i = 0; i < 4; i++) {
                bf16x8 a = *(const bf16x8*)(Ab + aoff[kk][i]);
                acc[i][0] = MFMA(a, b0, acc[i][0]);
                acc[i][1] = MFMA(a, b1, acc[i][1]);
            }
        }
    };

    // pipeline: 16 K-steps, ring of 2, 1-deep prefetch.
    // Outstanding at wait point = 12 (steps k and k+1); vmcnt(6) retires step k.
    VM_WAIT0;   // exact vmcnt baseline
    ISSUE(0, ring);
#pragma unroll
    for (int k = 0; k < 16; k++) {
        if (k + 1 < 16) ISSUE(k + 1, ring + ((k + 1) & 1) * SLOT);
        if (k < 15) { VM_WAIT6; } else { VM_WAIT0; }
        __builtin_amdgcn_s_barrier();
        compute(ring + (k & 1) * SLOT);
        __builtin_amdgcn_s_barrier();
    }
#undef ISSUE

    // epilogue: ring dead; reuse as gu
#pragma unroll
    for (int i = 0; i < 4; i++)
#pragma unroll
        for (int j = 0; j < 2; j++)
#pragma unroll
            for (int r = 0; r < 4; r++) {
                int mr = i * 16 + quad * 4 + r;
                int c = wid * 32 + j * 16 + lrow;
                u.gu[mr * 132 + c] = acc[i][j][r];
            }
    __syncthreads();

#pragma unroll
    for (int ii = 0; ii < 16; ii++) {
        int o = ii * 256 + tid;
        int mr = o >> 6, c = o & 63;
        if (m0 + mr < count) {
            float g  = u.gu[mr * 132 + c];
            float up = u.gu[mr * 132 + 64 + c];
            float a  = g / (1.0f + expf(-g)) * up;
            act[(size_t)(abase + m0 + mr) * I_DIM + n0 + c] = (__bf16)a;
        }
    }
}

// ---- GEMM2: out += w * (act @ w2d^T) -------------------------------------
// M=64 x N=128, K split in 2 halves of 6 K-steps (atomicAdd combine), so
// live blocks double to ~2/CU and the serial K-chain halves. Grid 2048:
// top bit = half (preserves bx&7 == v&7 XCD pinning).
__global__ __launch_bounds__(256, 3) void gemm2_kernel(
    const __bf16* __restrict__ act,
    const __bf16* __restrict__ w2d,
    const int* __restrict__ counts,
    const int* __restrict__ base,
    const int* __restrict__ tok_list,
    const float* __restrict__ wt_list,
    float* __restrict__ out)
{
    const int bx = blockIdx.x;
    const int h = bx >> 10;                // K-half: 0 or 1
    const int v = bx & 1023;
    const int xcd = v & 7, t = v >> 3;
    const int p = t & 7, m = t >> 3;       // 8 pairs per XCD, 16 m rounds
    const int P = xcd + 8 * p;             // pair id in [0,64)
    const int nb = P & 7, e = P >> 3;      // nb == xcd: n-slice pinned per XCD
    const int count = counts[e];
    const int m0 = m * 64;
    if (m0 >= count) return;
    const int n0 = nb * 128;
    const int abase = base[e];

    __shared__ uint4 r4[2 * SLOT / 16];    // 49152 B
    char* ring = (char*)r4;

    const int tid = threadIdx.x;
    const int wv = tid >> 6, ln = tid & 63;

    StgEnt se[6];
#pragma unroll
    for (int j = 0; j < 6; j++) {
        int off = wv * 6144 + j * 1024 + ln * 16;
        se[j].l = wv * 6144 + j * 1024;
        if (off < A_OFF) {
            int r = off >> 7, sl = (off >> 4) & 7, g = sl ^ (r & 7);
            se[j].p = (const char*)w2d + ((size_t)e * H_DIM + n0 + r) * 1536 + g * 16;
        } else {
            int ao = off - A_OFF, r = ao >> 7, sl = (ao >> 4) & 7, g = sl ^ (r & 7);
            int gr = abase + m0 + r; if (gr > 2 * T_TOK - 1) gr = 2 * T_TOK - 1;
            se[j].p = (const char*)act + (size_t)gr * 1536 + g * 16;
        }
        se[j].p += h * 768;                // K-half offset: 6 steps x 128 B
    }

#define ISSUE(kc, sb) do { \
        async16(se[0].p + (kc) * 128, (sb) + se[0].l); \
        async16(se[1].p + (kc) * 128, (sb) + se[1].l); \
        async16(se[2].p + (kc) * 128, (sb) + se[2].l); \
        async16(se[3].p + (kc) * 128, (sb) + se[3].l); \
        async16(se[4].p + (kc) * 128, (sb) + se[4].l); \
        async16(se[5].p + (kc) * 128, (sb) + se[5].l); } while (0)

    const int wid = wv, lane = ln, lrow = lane & 15, quad = lane >> 4;
    int aoff[2][4], boff[2][2];
#pragma unroll
    for (int kk = 0; kk < 2; kk++) {
        int gph = ((kk * 4 + quad) ^ (lrow & 7)) << 4;
#pragma unroll
        for (int i = 0; i < 4; i++) aoff[kk][i] = (i * 16 + lrow) * 128 + gph;
#pragma unroll
        for (int j = 0; j < 2; j++) boff[kk][j] = (wid * 32 + j * 16 + lrow) * 128 + gph;
    }

    f32x4 acc[4][2];
#pragma unroll
    for (int i = 0; i < 4; i++)
#pragma unroll
        for (int j = 0; j < 2; j++) { f32x4 z = {0.f, 0.f, 0.f, 0.f}; acc[i][j] = z; }

    auto compute = [&](const char* sb) {
        const char* Bb = sb;
        const char* Ab = sb + A_OFF;
#pragma unroll
        for (int kk = 0; kk < 2; kk++) {
            bf16x8 b0 = *(const bf16x8*)(Bb + boff[kk][0]);
            bf16x8 b1 = *(const bf16x8*)(Bb + boff[kk][1]);
#pragma unroll
            for (int i = 0; i < 4; i++) {
                bf16x8 a = *(const bf16x8*)(Ab + aoff[kk][i]);
                acc[i][0] = MFMA(a, b0, acc[i][0]);
                acc[i][1] = MFMA(a, b1, acc[i][1]);
            }
        }
    };

    // pipeline: 6 K-steps, ring of 2, 1-deep prefetch
    VM_WAIT0;
    ISSUE(0, ring);
#pragma unroll
    for (int k = 0; k < 6; k++) {
        if (k + 1 < 6) ISSUE(k + 1, ring + ((k + 1) & 1) * SLOT);
        if (k < 5) { VM_WAIT6; } else { VM_WAIT0; }
        __builtin_amdgcn_s_barrier();
        compute(ring + (k & 1) * SLOT);
        __builtin_amdgcn_s_barrier();
    }
#undef ISSUE

    // weighted atomic scatter (partial K-half sums commute)
#pragma unroll
    for (int i = 0; i < 4; i++)
#pragma unroll
        for (int r = 0; r < 4; r++) {
            int mr = i * 16 + quad * 4 + r;
            if (m0 + mr < count) {
                int   tk = tok_list[e * T_TOK + m0 + mr];
                float w  = wt_list[e * T_TOK + m0 + mr];
#pragma unroll
                for (int j = 0; j < 2; j++) {
                    int hh = n0 + wid * 32 + j * 16 + lrow;
                    atomicAdd(&out[(size_t)tk * H_DIM + hh], w * acc[i][j][r]);
                }
            }
        }
}

extern "C" void kernel_launch(void* const* d_in, const int* in_sizes, int n_in,
                              void* d_out, int out_size, void* d_ws, size_t ws_size,
                              hipStream_t stream) {
    (void)in_sizes; (void)n_in; (void)out_size; (void)ws_size;
    const float* x      = (const float*)d_in[0];
    const float* logits = (const float*)d_in[1];
    const float* w13    = (const float*)d_in[2];
    const float* w13s   = (const float*)d_in[3];
    const float* w2     = (const float*)d_in[4];
    const float* w2s    = (const float*)d_in[5];
    float* out = (float*)d_out;

    char* ws = (char*)d_ws;
    int*    counts   = (int*)ws;                              // @0
    int*    base     = (int*)(ws + 128);                      // @128
    int*    tok_list = (int*)(ws + 256);                      // 32 KB
    float*  wt_list  = (float*)(ws + 256 + 32768);            // 32 KB
    __bf16* act      = (__bf16*)(ws + 65792);                 // 3 MB
    __bf16* xbf      = (__bf16*)(ws + 65792 + 3145728);       // 2 MB
    __bf16* w13d     = (__bf16*)(ws + 65792 + 3145728 + 2097152);            // 25.2 MB
    __bf16* w2d      = (__bf16*)(ws + 65792 + 3145728 + 2097152 + 25165824); // 12.6 MB

    prep13_kernel<<<dim3(A_W13 + A_X + 1), 256, 0, stream>>>(
        w13, w13s, x, w13d, xbf,
        logits, counts, base, tok_list, wt_list);
    gemm1_kernel<<<dim3(GEMM1_BLOCKS + W2DQ_BLOCKS + ZERO_BLOCKS), 256, 0, stream>>>(
        xbf, w13d, counts, base, tok_list, act, w2, w2s, w2d, (float4*)out);
    gemm2_kernel<<<dim3(2048), 256, 0, stream>>>(
        act, w2d, counts, base, tok_list, wt_list, out);
}

// Round 12
// 150.761 us; speedup vs baseline: 4.4086x; 1.0290x over previous
//
#include <hip/hip_runtime.h>

#define T_TOK 1024
#define H_DIM 1024
#define I_DIM 768
#define E_NUM 8

// kernelA block ranges
#define A_W13 6144           // w13 dequant blocks (G13 groups / 256)
#define A_X   512            // x convert
#define A_Z   512            // out zero
#define G13 1572864          // 8*1536*1024/8
#define G2   786432          // 8*1024*768/8

// gemm1 grid: gemm blocks then w2-dequant blocks
#define GEMM1_BLOCKS 1536    // 8 xcd * 12 pairs * 16 m-rounds
#define W2DQ_BLOCKS  3072    // G2/256

#define SLOT 24576           // ring slot: B 16KB + A 8KB
#define A_OFF 16384

typedef __bf16 bf16x8 __attribute__((ext_vector_type(8)));
typedef float  f32x4  __attribute__((ext_vector_type(4)));

__device__ inline bf16x8 cvt8(float4 a, float4 b, float s) {
    bf16x8 o;
    o[0] = (__bf16)(a.x * s); o[1] = (__bf16)(a.y * s);
    o[2] = (__bf16)(a.z * s); o[3] = (__bf16)(a.w * s);
    o[4] = (__bf16)(b.x * s); o[5] = (__bf16)(b.y * s);
    o[6] = (__bf16)(b.z * s); o[7] = (__bf16)(b.w * s);
    return o;
}

// async 16B global -> LDS (linear dest: wave-uniform base + lane*16)
__device__ inline void async16(const void* g, void* l) {
    __builtin_amdgcn_global_load_lds(
        (const __attribute__((address_space(1))) unsigned int*)g,
        (__attribute__((address_space(3))) unsigned int*)l, 16, 0, 0);
}

#define VM_WAIT6  asm volatile("s_waitcnt vmcnt(6)"  ::: "memory")
#define VM_WAIT0  asm volatile("s_waitcnt vmcnt(0)"  ::: "memory")

// ---- kernelA: w13 dequant + x -> bf16 + zero out + router ----------------
__global__ __launch_bounds__(256) void prep13_kernel(
    const float* __restrict__ w13, const float* __restrict__ w13s,
    const float* __restrict__ x,   float4* __restrict__ out4,
    __bf16* __restrict__ w13d,     __bf16* __restrict__ xbf,
    const float* __restrict__ logits,
    int* __restrict__ counts, int* __restrict__ base,
    int* __restrict__ tok_list, float* __restrict__ wt_list)
{
    const int bx = blockIdx.x;
    if (bx < A_W13) {
        int g = bx * 256 + threadIdx.x;          // < G13
        int k8 = g & 127;                        // 128 groups per 1024-k row
        int row = g >> 7;                        // e*1536 + n
        float s = w13s[(row << 3) | (k8 >> 4)];
        const float4* src = (const float4*)w13 + (size_t)g * 2;
        *(bf16x8*)(w13d + (size_t)g * 8) = cvt8(src[0], src[1], s);
        return;
    }
    if (bx < A_W13 + A_X) {
        int g = (bx - A_W13) * 256 + threadIdx.x;   // < 131072
        const float4* src = (const float4*)x + (size_t)g * 2;
        *(bf16x8*)(xbf + (size_t)g * 8) = cvt8(src[0], src[1], 1.0f);
        return;
    }
    if (bx < A_W13 + A_X + A_Z) {
        int go = (bx - A_W13 - A_X) * 256 + threadIdx.x;  // < 131072, 32B each
        float4 z = make_float4(0.f, 0.f, 0.f, 0.f);
        out4[2 * go] = z; out4[2 * go + 1] = z;
        return;
    }
    // ---- router (single block) ----
    __shared__ int cnt[E_NUM];
    const int t0 = threadIdx.x;
    if (t0 < E_NUM) cnt[t0] = 0;
    __syncthreads();
#pragma unroll
    for (int tt = 0; tt < 4; tt++) {
        int t = t0 + tt * 256;
        float l[E_NUM];
#pragma unroll
        for (int e = 0; e < E_NUM; e++) l[e] = logits[t * E_NUM + e];
        int e0 = 0; float m0 = l[0];
#pragma unroll
        for (int e = 1; e < E_NUM; e++) if (l[e] > m0) { m0 = l[e]; e0 = e; }
        int e1 = -1; float m1 = -3e38f;
#pragma unroll
        for (int e = 0; e < E_NUM; e++) if (e != e0 && l[e] > m1) { m1 = l[e]; e1 = e; }
        float w0 = 1.0f / (1.0f + expf(m1 - m0));
        float w1 = 1.0f - w0;
        int p0 = atomicAdd(&cnt[e0], 1);
        tok_list[e0 * T_TOK + p0] = t;
        wt_list[e0 * T_TOK + p0] = w0;
        int p1 = atomicAdd(&cnt[e1], 1);
        tok_list[e1 * T_TOK + p1] = t;
        wt_list[e1 * T_TOK + p1] = w1;
    }
    __syncthreads();
    if (t0 == 0) {
        int s = 0;
        for (int e = 0; e < E_NUM; e++) { base[e] = s; counts[e] = cnt[e]; s += cnt[e]; }
    }
}

#define MFMA(A, B, C) __builtin_amdgcn_mfma_f32_16x16x32_bf16(A, B, C, 0, 0, 0)

// Per-thread staging entry: global byte ptr (at K-chunk 0) + wave-uniform LDS
// byte offset within slot. Inverse-swizzled SOURCE + linear LDS dest + the
// proven swizzled ds_read offsets (both-sides-or-neither rule).
struct StgEnt { const char* p; int l; };

// ---- kernelB: GEMM1 (M=64 x N=128, BK=64) + appended w2-dequant ----------
// gload_lds staging, 2-slot LDS ring (49 KB -> 3 blocks/CU), counted vmcnt
// (never 0 in loop), raw s_barrier.
__global__ __launch_bounds__(256, 3) void gemm1_kernel(
    const __bf16* __restrict__ xbf,
    const __bf16* __restrict__ w13d,
    const int* __restrict__ counts,
    const int* __restrict__ base,
    const int* __restrict__ tok_list,
    __bf16* __restrict__ act,
    const float* __restrict__ w2,
    const float* __restrict__ w2s,
    __bf16* __restrict__ w2d)
{
    const int bx = blockIdx.x;
    if (bx >= GEMM1_BLOCKS) {
        // ---- w2 dequant (no dependency on gemm1; fills idle CUs) ----
        int g2 = (bx - GEMM1_BLOCKS) * 256 + threadIdx.x;   // < G2
        unsigned row = (unsigned)g2 / 96u;   // e*1024 + h
        int k8 = g2 - row * 96;
        float s = w2s[row * 6 + (k8 >> 4)];
        const float4* src = (const float4*)w2 + (size_t)g2 * 2;
        *(bf16x8*)(w2d + (size_t)g2 * 8) = cvt8(src[0], src[1], s);
        return;
    }

    const int xcd = bx & 7, t = bx >> 3;
    const int p = t % 12, m = t / 12;      // 12 pairs per XCD, 16 m rounds
    const int P = xcd + 8 * p;             // pair id in [0,96)
    const int nb = P % 12, e = P / 12;
    const int count = counts[e];
    const int m0 = m * 64;
    if (m0 >= count) return;
    const int n0 = nb * 64;
    const int abase = base[e];

    __shared__ union { uint4 r4[2 * SLOT / 16]; float gu[64 * 132]; } u;  // 49152 B
    __shared__ int tokS[64];
    char* ring = (char*)u.r4;

    const int tid = threadIdx.x;
    if (tid < 64) {
        int r = m0 + tid;
        tokS[tid] = (r < count) ? tok_list[e * T_TOK + r] : tok_list[e * T_TOK];
    }
    __syncthreads();   // also drains vmcnt -> clean pipeline baseline

    const int wv = tid >> 6, ln = tid & 63;
    // 6 staging calls per thread: bytes [wv*6144 + j*1024 + ln*16) of slot.
    // B region [0,16384): LDS row r (128B), slot s holds global granule s^(r&7).
    // A region [16384,24576): same per-row swizzle, rows = tokS.
    StgEnt se[6];
#pragma unroll
    for (int j = 0; j < 6; j++) {
        int off = wv * 6144 + j * 1024 + ln * 16;
        se[j].l = wv * 6144 + j * 1024;          // wave-uniform dest
        if (off < A_OFF) {
            int r = off >> 7, sl = (off >> 4) & 7, g = sl ^ (r & 7);
            int nB = (r < 64) ? (n0 + r) : (I_DIM + n0 + r - 64);
            se[j].p = (const char*)w13d + ((size_t)e * 2 * I_DIM + nB) * 2048 + g * 16;
        } else {
            int ao = off - A_OFF, r = ao >> 7, sl = (ao >> 4) & 7, g = sl ^ (r & 7);
            se[j].p = (const char*)xbf + (size_t)tokS[r] * 2048 + g * 16;
        }
    }

#define ISSUE(kc, sb) do { \
        async16(se[0].p + (kc) * 128, (sb) + se[0].l); \
        async16(se[1].p + (kc) * 128, (sb) + se[1].l); \
        async16(se[2].p + (kc) * 128, (sb) + se[2].l); \
        async16(se[3].p + (kc) * 128, (sb) + se[3].l); \
        async16(se[4].p + (kc) * 128, (sb) + se[4].l); \
        async16(se[5].p + (kc) * 128, (sb) + se[5].l); } while (0)

    const int wid = wv, lane = ln, lrow = lane & 15, quad = lane >> 4;
    int aoff[2][4], boff[2][2];
#pragma unroll
    for (int kk = 0; kk < 2; kk++) {
        int gph = ((kk * 4 + quad) ^ (lrow & 7)) << 4;
#pragma unroll
        for (int i = 0; i < 4; i++) aoff[kk][i] = (i * 16 + lrow) * 128 + gph;
#pragma unroll
        for (int j = 0; j < 2; j++) boff[kk][j] = (wid * 32 + j * 16 + lrow) * 128 + gph;
    }

    f32x4 acc[4][2];
#pragma unroll
    for (int i = 0; i < 4; i++)
#pragma unroll
        for (int j = 0; j < 2; j++) { f32x4 z = {0.f, 0.f, 0.f, 0.f}; acc[i][j] = z; }

    auto compute = [&](const char* sb) {
        const char* Bb = sb;
        const char* Ab = sb + A_OFF;
#pragma unroll
        for (int kk = 0; kk < 2; kk++) {
            bf16x8 b0 = *(const bf16x8*)(Bb + boff[kk][0]);
            bf16x8 b1 = *(const bf16x8*)(Bb + boff[kk][1]);
#pragma unroll
            for (int i = 0; i < 4; i++) {
                bf16x8 a = *(const bf16x8*)(Ab + aoff[kk][i]);
                acc[i][0] = MFMA(a, b0, acc[i][0]);
                acc[i][1] = MFMA(a, b1, acc[i][1]);
            }
        }
    };

    // pipeline: 16 K-steps, ring of 2, 1-deep prefetch.
    // Outstanding at wait point = 12 (steps k and k+1); vmcnt(6) retires step k.
    VM_WAIT0;   // exact vmcnt baseline
    ISSUE(0, ring);
#pragma unroll
    for (int k = 0; k < 16; k++) {
        if (k + 1 < 16) ISSUE(k + 1, ring + ((k + 1) & 1) * SLOT);
        if (k < 15) { VM_WAIT6; } else { VM_WAIT0; }
        __builtin_amdgcn_s_barrier();
        compute(ring + (k & 1) * SLOT);
        __builtin_amdgcn_s_barrier();
    }
#undef ISSUE

    // epilogue: ring dead; reuse as gu
#pragma unroll
    for (int i = 0; i < 4; i++)
#pragma unroll
        for (int j = 0; j < 2; j++)
#pragma unroll
            for (int r = 0; r < 4; r++) {
                int mr = i * 16 + quad * 4 + r;
                int c = wid * 32 + j * 16 + lrow;
                u.gu[mr * 132 + c] = acc[i][j][r];
            }
    __syncthreads();

#pragma unroll
    for (int ii = 0; ii < 16; ii++) {
        int o = ii * 256 + tid;
        int mr = o >> 6, c = o & 63;
        if (m0 + mr < count) {
            float g  = u.gu[mr * 132 + c];
            float up = u.gu[mr * 132 + 64 + c];
            float a  = g / (1.0f + expf(-g)) * up;
            act[(size_t)(abase + m0 + mr) * I_DIM + n0 + c] = (__bf16)a;
        }
    }
}

// ---- GEMM2: out += w * (act @ w2d^T) -------------------------------------
// M=64 x N=128, BK=64, 12 K-steps; same ring-2 gload_lds pipeline, 3/CU.
__global__ __launch_bounds__(256, 3) void gemm2_kernel(
    const __bf16* __restrict__ act,
    const __bf16* __restrict__ w2d,
    const int* __restrict__ counts,
    const int* __restrict__ base,
    const int* __restrict__ tok_list,
    const float* __restrict__ wt_list,
    float* __restrict__ out)
{
    const int bx = blockIdx.x;
    const int xcd = bx & 7, t = bx >> 3;
    const int p = t & 7, m = t >> 3;       // 8 pairs per XCD, 16 m rounds
    const int P = xcd + 8 * p;             // pair id in [0,64)
    const int nb = P & 7, e = P >> 3;      // nb == xcd: n-slice pinned per XCD
    const int count = counts[e];
    const int m0 = m * 64;
    if (m0 >= count) return;
    const int n0 = nb * 128;
    const int abase = base[e];

    __shared__ uint4 r4[2 * SLOT / 16];    // 49152 B
    char* ring = (char*)r4;

    const int tid = threadIdx.x;
    const int wv = tid >> 6, ln = tid & 63;

    StgEnt se[6];
#pragma unroll
    for (int j = 0; j < 6; j++) {
        int off = wv * 6144 + j * 1024 + ln * 16;
        se[j].l = wv * 6144 + j * 1024;
        if (off < A_OFF) {
            int r = off >> 7, sl = (off >> 4) & 7, g = sl ^ (r & 7);
            se[j].p = (const char*)w2d + ((size_t)e * H_DIM + n0 + r) * 1536 + g * 16;
        } else {
            int ao = off - A_OFF, r = ao >> 7, sl = (ao >> 4) & 7, g = sl ^ (r & 7);
            int gr = abase + m0 + r; if (gr > 2 * T_TOK - 1) gr = 2 * T_TOK - 1;
            se[j].p = (const char*)act + (size_t)gr * 1536 + g * 16;
        }
    }

#define ISSUE(kc, sb) do { \
        async16(se[0].p + (kc) * 128, (sb) + se[0].l); \
        async16(se[1].p + (kc) * 128, (sb) + se[1].l); \
        async16(se[2].p + (kc) * 128, (sb) + se[2].l); \
        async16(se[3].p + (kc) * 128, (sb) + se[3].l); \
        async16(se[4].p + (kc) * 128, (sb) + se[4].l); \
        async16(se[5].p + (kc) * 128, (sb) + se[5].l); } while (0)

    const int wid = wv, lane = ln, lrow = lane & 15, quad = lane >> 4;
    int aoff[2][4], boff[2][2];
#pragma unroll
    for (int kk = 0; kk < 2; kk++) {
        int gph = ((kk * 4 + quad) ^ (lrow & 7)) << 4;
#pragma unroll
        for (int i = 0; i < 4; i++) aoff[kk][i] = (i * 16 + lrow) * 128 + gph;
#pragma unroll
        for (int j = 0; j < 2; j++) boff[kk][j] = (wid * 32 + j * 16 + lrow) * 128 + gph;
    }

    f32x4 acc[4][2];
#pragma unroll
    for (int i = 0; i < 4; i++)
#pragma unroll
        for (int j = 0; j < 2; j++) { f32x4 z = {0.f, 0.f, 0.f, 0.f}; acc[i][j] = z; }

    auto compute = [&](const char* sb) {
        const char* Bb = sb;
        const char* Ab = sb + A_OFF;
#pragma unroll
        for (int kk = 0; kk < 2; kk++) {
            bf16x8 b0 = *(const bf16x8*)(Bb + boff[kk][0]);
            bf16x8 b1 = *(const bf16x8*)(Bb + boff[kk][1]);
#pragma unroll
            for (int i = 0; i < 4; i++) {
                bf16x8 a = *(const bf16x8*)(Ab + aoff[kk][i]);
                acc[i][0] = MFMA(a, b0, acc[i][0]);
                acc[i][1] = MFMA(a, b1, acc[i][1]);
            }
        }
    };

    // pipeline: 12 K-steps, ring of 2, 1-deep prefetch
    VM_WAIT0;
    ISSUE(0, ring);
#pragma unroll
    for (int k = 0; k < 12; k++) {
        if (k + 1 < 12) ISSUE(k + 1, ring + ((k + 1) & 1) * SLOT);
        if (k < 11) { VM_WAIT6; } else { VM_WAIT0; }
        __builtin_amdgcn_s_barrier();
        compute(ring + (k & 1) * SLOT);
        __builtin_amdgcn_s_barrier();
    }
#undef ISSUE

    // weighted atomic scatter
#pragma unroll
    for (int i = 0; i < 4; i++)
#pragma unroll
        for (int r = 0; r < 4; r++) {
            int mr = i * 16 + quad * 4 + r;
            if (m0 + mr < count) {
                int   tk = tok_list[e * T_TOK + m0 + mr];
                float w  = wt_list[e * T_TOK + m0 + mr];
#pragma unroll
                for (int j = 0; j < 2; j++) {
                    int h = n0 + wid * 32 + j * 16 + lrow;
                    atomicAdd(&out[(size_t)tk * H_DIM + h], w * acc[i][j][r]);
                }
            }
        }
}

extern "C" void kernel_launch(void* const* d_in, const int* in_sizes, int n_in,
                              void* d_out, int out_size, void* d_ws, size_t ws_size,
                              hipStream_t stream) {
    (void)in_sizes; (void)n_in; (void)out_size; (void)ws_size;
    const float* x      = (const float*)d_in[0];
    const float* logits = (const float*)d_in[1];
    const float* w13    = (const float*)d_in[2];
    const float* w13s   = (const float*)d_in[3];
    const float* w2     = (const float*)d_in[4];
    const float* w2s    = (const float*)d_in[5];
    float* out = (float*)d_out;

    char* ws = (char*)d_ws;
    int*    counts   = (int*)ws;                              // @0
    int*    base     = (int*)(ws + 128);                      // @128
    int*    tok_list = (int*)(ws + 256);                      // 32 KB
    float*  wt_list  = (float*)(ws + 256 + 32768);            // 32 KB
    __bf16* act      = (__bf16*)(ws + 65792);                 // 3 MB
    __bf16* xbf      = (__bf16*)(ws + 65792 + 3145728);       // 2 MB
    __bf16* w13d     = (__bf16*)(ws + 65792 + 3145728 + 2097152);            // 25.2 MB
    __bf16* w2d      = (__bf16*)(ws + 65792 + 3145728 + 2097152 + 25165824); // 12.6 MB

    prep13_kernel<<<dim3(A_W13 + A_X + A_Z + 1), 256, 0, stream>>>(
        w13, w13s, x, (float4*)out, w13d, xbf,
        logits, counts, base, tok_list, wt_list);
    gemm1_kernel<<<dim3(GEMM1_BLOCKS + W2DQ_BLOCKS), 256, 0, stream>>>(
        xbf, w13d, counts, base, tok_list, act, w2, w2s, w2d);
    gemm2_kernel<<<dim3(1024), 256, 0, stream>>>(
        act, w2d, counts, base, tok_list, wt_list, out);
}